// Round 15
// baseline (21.494 us; speedup 1.0000x reference)
//
#include <hip/hip_runtime.h>

constexpr int NQ = 7;
constexpr int NL = 4;
constexpr int NG = NL * NQ;   // 28
constexpr int NCLS = 22;
constexpr int EPB = 8;        // elements per 256-thread block (one per 32-lane half)

typedef float v2 __attribute__((ext_vector_type(2)));
#define FMA2(a,b,c) __builtin_elementwise_fma((a),(b),(c))

__device__ __forceinline__ v2 sp(float s) { v2 r; r.x = s; r.y = s; return r; }

// ---------------- cross-lane primitives (all HW-proven R1..R14) ----------------
template<int CTRL>
__device__ __forceinline__ float fdpp(float v) {
    return __int_as_float(__builtin_amdgcn_mov_dpp(__float_as_int(v), CTRL, 0xF, 0xF, true));
}
template<int OFF>
__device__ __forceinline__ float fswz(float v) {
    return __int_as_float(__builtin_amdgcn_ds_swizzle(__float_as_int(v), OFF));
}
template<int M>
__device__ __forceinline__ float xorl(float v) {
    if      constexpr (M == 1)  return fdpp<0xB1>(v);    // quad_perm [1,0,3,2]
    else if constexpr (M == 2)  return fdpp<0x4E>(v);    // quad_perm [2,3,0,1]
    else if constexpr (M == 4)  return fswz<0x101F>(v);  // xor4 (swizzle)
    else if constexpr (M == 8)  return fdpp<0x128>(v);   // ROW_ROR:8 == xor8
    else                        return fswz<0x401F>(v);  // xor16 (swizzle)
}
template<int M>
__device__ __forceinline__ v2 shufv(v2 v) {
    v2 r; r.x = xorl<M>(v.x); r.y = xorl<M>(v.y); return r;
}

// ---------------- fused gate build: U' = U_rot @ RX(c,s) ----------------
__device__ __forceinline__ void fuse(const float* __restrict__ u, float c, float s,
                                     float4& A, float4& B) {
    A.x = fmaf(c, u[0],  s * u[3]);  A.y = fmaf(c, u[1], -s * u[2]);
    A.z = fmaf(c, u[2],  s * u[1]);  A.w = fmaf(c, u[3], -s * u[0]);
    B.x = fmaf(c, u[4],  s * u[7]);  B.y = fmaf(c, u[5], -s * u[6]);
    B.z = fmaf(c, u[6],  s * u[5]);  B.w = fmaf(c, u[7], -s * u[4]);
}

// lane-bit gate (mask M): packed state (2 v2 regs each for re/im)
template<int M>
__device__ __forceinline__ void gateLane(int lane, float4 A, float4 B,
                                         v2 X[2], v2 Y[2]) {
    const bool hi = (lane & M) != 0;
    const float cvr = hi ? B.z : A.x, cvi = hi ? B.w : A.y;   // diag
    const float cwr = hi ? B.x : A.z, cwi = hi ? B.y : A.w;   // off-diag
    v2 Xs[2], Ys[2];
    #pragma unroll
    for (int j = 0; j < 2; ++j) { Xs[j] = shufv<M>(X[j]); Ys[j] = shufv<M>(Y[j]); }
    #pragma unroll
    for (int j = 0; j < 2; ++j) {
        v2 nX = FMA2(sp(cvr), X[j], FMA2(sp(-cvi), Y[j], FMA2(sp(cwr), Xs[j], sp(-cwi)*Ys[j])));
        v2 nY = FMA2(sp(cvr), Y[j], FMA2(sp( cvi), X[j], FMA2(sp(cwr), Ys[j], sp( cwi)*Xs[j])));
        X[j] = nX; Y[j] = nY;
    }
}

// cross-register gate (reg a = row-0 role, reg b = row-1 role)
__device__ __forceinline__ void gateCross(float4 A, float4 B,
                                          v2& Xa, v2& Ya, v2& Xb, v2& Yb) {
    v2 nXa = FMA2(sp(A.x), Xa, FMA2(sp(-A.y), Ya, FMA2(sp(A.z), Xb, sp(-A.w)*Yb)));
    v2 nYa = FMA2(sp(A.x), Ya, FMA2(sp( A.y), Xa, FMA2(sp(A.z), Yb, sp( A.w)*Xb)));
    v2 nXb = FMA2(sp(B.x), Xa, FMA2(sp(-B.y), Ya, FMA2(sp(B.z), Xb, sp(-B.w)*Yb)));
    v2 nYb = FMA2(sp(B.x), Ya, FMA2(sp( B.y), Xa, FMA2(sp(B.z), Yb, sp( B.w)*Xb)));
    Xa = nXa; Ya = nYa; Xb = nXb; Yb = nYb;
}

// ---------------- main kernel: TWO elements per wave, packed re/im ----------------
// element = 32-lane half; within-half lane wl = lane&31.
// amp a6..a0 = w4 w3 w2 w1 w0 k1 k0. Component = k1, register j = k0.
//   X[j] = (re[k1=0,k0=j], re[k1=1,k0=j]), Y[j] = imag pair.
// qubit q0->w4(m16) q1->w3(m8) q2->w2(m4) q3->w1(m2) q4->w0(m1)
//       q5->k1(component) q6->k0(register)
__global__ __launch_bounds__(256, 8) void reupload_kernel(
    const float* __restrict__ x,       // (B,7)
    const float* __restrict__ wts,     // (4,7,3)
    const float* __restrict__ fc1_w,   // (32,7)
    const float* __restrict__ fc1_b,   // (32,)
    const float* __restrict__ fc2_w,   // (22,32)
    const float* __restrict__ fc2_b,   // (22,)
    float* __restrict__ out,           // (B,22)
    int B)
{
    __shared__ __align__(16) float rotU[NG * 8];        // 28 Rot matrices (896 B)
    __shared__ float2 csb[EPB * NQ];                    // per-element RX (448 B)
    __shared__ __align__(16) float fU[NG * EPB * 8];    // fused matrices (7 KB)
    __shared__ __align__(16) float fUT[NL * EPB * 8];   // q5 transposed coefs (1 KB)
    __shared__ __align__(16) float hbuf[EPB][32];       // MLP hidden (1 KB)

    const int tid = threadIdx.x;
    // --- phase 0: c,s (56 thr, wave 0) ∥ Rot matrices (28 thr, wave 1) ---
    if (tid < EPB * NQ) {
        const int e = tid / NQ, q = tid % NQ;
        const int bb = blockIdx.x * EPB + e;
        const float xv = (bb < B) ? x[bb*NQ + q] : 0.f;
        const float h = 0.5f * xv;
        csb[tid] = make_float2(__cosf(h), __sinf(h));
    } else if (tid >= 64 && tid < 64 + NG) {
        const int g = tid - 64;
        float phi = wts[g*3+0], th = wts[g*3+1], om = wts[g*3+2];
        float ct = __cosf(0.5f*th), st = __sinf(0.5f*th);
        float ap = 0.5f*(phi+om),  am = 0.5f*(phi-om);
        float cp = __cosf(ap), sp_ = __sinf(ap);
        float cm = __cosf(am), sm = __sinf(am);
        float* u = &rotU[g*8];
        u[0] =  cp*ct; u[1] = -sp_*ct;  // u00 = ep*ct        (ep = cp - i sp)
        u[2] = -cm*st; u[3] = -sm*st;   // u01 = -conj(em)*st (em = cm - i sm)
        u[4] =  cm*st; u[5] = -sm*st;   // u10 = em*st
        u[6] =  cp*ct; u[7] =  sp_*ct;  // u11 = conj(ep)*ct
    }
    __syncthreads();
    // --- phase 1: build fused matrices (224 jobs, 1/thread); q5 also transposed ---
    if (tid < NG * EPB) {
        const int g = tid >> 3, e = tid & 7;
        const int q = g % NQ;
        const float2 cs = csb[e*NQ + q];
        float4 A, Bq;
        fuse(&rotU[g*8], cs.x, cs.y, A, Bq);
        float4* dst = reinterpret_cast<float4*>(&fU[(g*EPB + e)*8]);
        dst[0] = A; dst[1] = Bq;
        if (q == 5) {   // {(u00r,u10r),(u00i,u10i),(u01r,u11r),(u01i,u11i)}
            const int l = g / NQ;
            float* td = &fUT[(l*EPB + e)*8];
            td[0] = A.x; td[1] = Bq.x; td[2] = A.y; td[3] = Bq.y;
            td[4] = A.z; td[5] = Bq.z; td[6] = A.w; td[7] = Bq.w;
        }
    }
    __syncthreads();

    const int lane = threadIdx.x & 63;
    const int wl   = threadIdx.x & 31;          // within-half lane
    const int grp  = threadIdx.x >> 5;          // element slot in block (0..7)
    const int b    = blockIdx.x * EPB + grp;
    if (b >= B) return;

    // merged CNOT(0,1)(1,2)(2,3)(3,4) gather: src_w = wl ^ (wl>>1) (R13-proven)
    const int srcLane = (lane & 32) | ((wl ^ (wl >> 1)) & 31);

    // |0..0>: amp 0 -> reg 0 comp .x at wl==0
    v2 X[2], Y[2];
    X[0] = sp(0.f); X[1] = sp(0.f); Y[0] = sp(0.f); Y[1] = sp(0.f);
    X[0].x = (wl == 0) ? 1.f : 0.f;

    #pragma unroll
    for (int l = 0; l < NL; ++l) {
        float4 A, Bq;
        #define LOADU(q) { const float4* up = reinterpret_cast<const float4*>( \
            &fU[((l*NQ + (q))*EPB + grp)*8]); A = up[0]; Bq = up[1]; }
        LOADU(0); gateLane<16>(lane, A, Bq, X, Y);  // q0 -> w4 (swz)
        LOADU(1); gateLane< 8>(lane, A, Bq, X, Y);  // q1 -> w3 (DPP)
        LOADU(2); gateLane< 4>(lane, A, Bq, X, Y);  // q2 -> w2 (swz)
        LOADU(3); gateLane< 2>(lane, A, Bq, X, Y);  // q3 -> w1 (DPP)
        LOADU(4); gateLane< 1>(lane, A, Bq, X, Y);  // q4 -> w0 (DPP)
        {   // q5 -> k1 (component): paired coefficients (R14-proven form)
            const v2* tp = reinterpret_cast<const v2*>(&fUT[(l*EPB + grp)*8]);
            const v2 c00r = tp[0], c00i = tp[1], c01r = tp[2], c01i = tp[3];
            #pragma unroll
            for (int j = 0; j < 2; ++j) {
                const v2 Xxx = X[j].xx, Xyy = X[j].yy;
                const v2 Yxx = Y[j].xx, Yyy = Y[j].yy;
                v2 nX = FMA2(c00r, Xxx, FMA2(-c00i, Yxx, FMA2(c01r, Xyy, (-c01i)*Yyy)));
                v2 nY = FMA2(c00r, Yxx, FMA2( c00i, Xxx, FMA2(c01r, Yyy, ( c01i)*Xyy)));
                X[j] = nX; Y[j] = nY;
            }
        }
        LOADU(6);                                   // q6 -> k0 (register)
        gateCross(A, Bq, X[0], Y[0], X[1], Y[1]);
        #undef LOADU

        // --- CNOT ring CNOT(q, q+1 mod 7), reference order q=0..6 ---
        // (0,1)+(1,2)+(2,3)+(3,4) merged: new[w] = old[w ^ (w>>1)] — one gather
        #pragma unroll
        for (int j = 0; j < 2; ++j) {
            X[j].x = __shfl(X[j].x, srcLane); X[j].y = __shfl(X[j].y, srcLane);
            Y[j].x = __shfl(Y[j].x, srcLane); Y[j].y = __shfl(Y[j].y, srcLane);
        }
        {   // (4,5): ctrl w0 (lane&1), tgt k1 -> conditional component swap
            const bool cc = (lane & 1) != 0;
            #pragma unroll
            for (int j = 0; j < 2; ++j) {
                v2 xs = X[j].yx, ys = Y[j].yx;
                X[j].x = cc ? xs.x : X[j].x;  X[j].y = cc ? xs.y : X[j].y;
                Y[j].x = cc ? ys.x : Y[j].x;  Y[j].y = cc ? ys.y : Y[j].y;
            }
        }
        {   // (5,6): ctrl k1 (.y comps), tgt k0 -> swap .y between regs 0,1
            float t;
            t = X[0].y; X[0].y = X[1].y; X[1].y = t;
            t = Y[0].y; Y[0].y = Y[1].y; Y[1].y = t;
        }
        {   // (6,0): ctrl k0 (reg 1), tgt w4 -> reg 1 swaps across mask16
            X[1] = shufv<16>(X[1]);
            Y[1] = shufv<16>(Y[1]);
        }
    }

    // ---------- <Z_j> ----------
    v2 P[2];
    #pragma unroll
    for (int j = 0; j < 2; ++j) P[j] = FMA2(X[j], X[j], Y[j]*Y[j]);
    const v2 T = P[0] + P[1];
    const float t = T.x + T.y;
    float z[NQ];
    z[0] = (lane & 16) ? -t : t;
    z[1] = (lane &  8) ? -t : t;
    z[2] = (lane &  4) ? -t : t;
    z[3] = (lane &  2) ? -t : t;
    z[4] = (lane &  1) ? -t : t;
    z[5] = T.x - T.y;                                   // sign by k1 (component)
    z[6] = (P[0].x + P[0].y) - (P[1].x + P[1].y);       // sign by k0 (register)
    // 32-lane reduction (R13-proven): xor1, xor2 DPP; ror4/8/12 for 16; xor16 swz
    #pragma unroll
    for (int j = 0; j < NQ; ++j) {
        float v = z[j];
        v += xorl<1>(v);
        v += xorl<2>(v);
        const float q4  = fdpp<0x124>(v);
        const float q8  = fdpp<0x128>(v);
        const float q12 = fdpp<0x12C>(v);
        v = (v + q8) + (q4 + q12);
        v += fswz<0x401F>(v);
        z[j] = v;   // per-element sum in every lane of the half
    }

    // ---------- MLP 7 -> 32(relu) -> 22, per 32-lane half ----------
    float acc1 = fc1_b[wl];
    #pragma unroll
    for (int j = 0; j < NQ; ++j) acc1 = fmaf(z[j], fc1_w[wl*NQ + j], acc1);
    hbuf[grp][wl] = fmaxf(acc1, 0.f);
    __builtin_amdgcn_wave_barrier();
    asm volatile("s_waitcnt lgkmcnt(0)" ::: "memory");
    __builtin_amdgcn_sched_barrier(0);

    float hv[32];
    #pragma unroll
    for (int i = 0; i < 8; ++i) {   // broadcast reads within each half
        float4 v4 = *reinterpret_cast<const float4*>(&hbuf[grp][i*4]);
        hv[i*4+0] = v4.x; hv[i*4+1] = v4.y; hv[i*4+2] = v4.z; hv[i*4+3] = v4.w;
    }
    const int k = (wl < NCLS) ? wl : 0;
    float acc2 = fc2_b[k];
    const float4* w4 = reinterpret_cast<const float4*>(fc2_w + k*32);
    #pragma unroll
    for (int i = 0; i < 8; ++i) {
        float4 wv = w4[i];
        acc2 = fmaf(hv[i*4+0], wv.x, acc2);
        acc2 = fmaf(hv[i*4+1], wv.y, acc2);
        acc2 = fmaf(hv[i*4+2], wv.z, acc2);
        acc2 = fmaf(hv[i*4+3], wv.w, acc2);
    }
    if (wl < NCLS) out[b*NCLS + wl] = acc2;
}

extern "C" void kernel_launch(void* const* d_in, const int* in_sizes, int n_in,
                              void* d_out, int out_size, void* d_ws, size_t ws_size,
                              hipStream_t stream) {
    const float* x     = (const float*)d_in[0];
    const float* wts   = (const float*)d_in[1];
    const float* fc1_w = (const float*)d_in[2];
    const float* fc1_b = (const float*)d_in[3];
    const float* fc2_w = (const float*)d_in[4];
    const float* fc2_b = (const float*)d_in[5];
    float* out = (float*)d_out;

    const int B = in_sizes[0] / NQ;            // 16384
    const int grid = (B + EPB - 1) / EPB;      // 2048 blocks -> 8 blocks/CU
    reupload_kernel<<<grid, 256, 0, stream>>>(x, wts, fc1_w, fc1_b, fc2_w, fc2_b, out, B);
}

// Round 16
// 20.108 us; speedup vs baseline: 1.0689x; 1.0689x over previous
//
#include <hip/hip_runtime.h>

constexpr int NQ = 7;
constexpr int NL = 4;
constexpr int NG = NL * NQ;   // 28
constexpr int NCLS = 22;
constexpr int EPB = 16;       // elements per 256-thread block (one per 16-lane group)

typedef float v2 __attribute__((ext_vector_type(2)));
#define FMA2(a,b,c) __builtin_elementwise_fma((a),(b),(c))

__device__ __forceinline__ v2 sp(float s) { v2 r; r.x = s; r.y = s; return r; }
__device__ __forceinline__ v2 mkv2(float a, float b) { v2 r; r.x = a; r.y = b; return r; }
__device__ __forceinline__ v2 sel(bool c, v2 a, v2 b) {
    v2 r; r.x = c ? a.x : b.x; r.y = c ? a.y : b.y; return r;
}

// ---------------- cross-lane primitives (all HW-proven R1..R15) ----------------
template<int CTRL>
__device__ __forceinline__ float fdpp(float v) {
    return __int_as_float(__builtin_amdgcn_mov_dpp(__float_as_int(v), CTRL, 0xF, 0xF, true));
}
template<int OFF>
__device__ __forceinline__ float fswz(float v) {
    return __int_as_float(__builtin_amdgcn_ds_swizzle(__float_as_int(v), OFF));
}
template<int M>
__device__ __forceinline__ float xorl(float v) {
    if      constexpr (M == 1)  return fdpp<0xB1>(v);    // quad_perm [1,0,3,2]
    else if constexpr (M == 2)  return fdpp<0x4E>(v);    // quad_perm [2,3,0,1]
    else if constexpr (M == 4)  return fswz<0x101F>(v);  // xor4
    else                        return fdpp<0x128>(v);   // ROW_ROR:8 == xor8 (R12-proven)
}
template<int M>
__device__ __forceinline__ v2 shufv(v2 v) {
    v2 r; r.x = xorl<M>(v.x); r.y = xorl<M>(v.y); return r;
}

// ---------------- fused gate build: U' = U_rot @ RX(c,s) ----------------
__device__ __forceinline__ void fuse(const float* __restrict__ u, float c, float s,
                                     float4& A, float4& B) {
    A.x = fmaf(c, u[0],  s * u[3]);  A.y = fmaf(c, u[1], -s * u[2]);
    A.z = fmaf(c, u[2],  s * u[1]);  A.w = fmaf(c, u[3], -s * u[0]);
    B.x = fmaf(c, u[4],  s * u[7]);  B.y = fmaf(c, u[5], -s * u[6]);
    B.z = fmaf(c, u[6],  s * u[5]);  B.w = fmaf(c, u[7], -s * u[4]);
}

// lane-bit gate (mask M): packed state, scalar coefficient broadcast
template<int M>
__device__ __forceinline__ void gateLane(int lane, float4 A, float4 B,
                                         v2 X[4], v2 Y[4]) {
    const bool hi = (lane & M) != 0;
    const float cvr = hi ? B.z : A.x, cvi = hi ? B.w : A.y;   // diag
    const float cwr = hi ? B.x : A.z, cwi = hi ? B.y : A.w;   // off-diag
    v2 Xs[4], Ys[4];
    #pragma unroll
    for (int j = 0; j < 4; ++j) { Xs[j] = shufv<M>(X[j]); Ys[j] = shufv<M>(Y[j]); }
    #pragma unroll
    for (int j = 0; j < 4; ++j) {
        v2 nX = FMA2(sp(cvr), X[j], FMA2(sp(-cvi), Y[j], FMA2(sp(cwr), Xs[j], sp(-cwi)*Ys[j])));
        v2 nY = FMA2(sp(cvr), Y[j], FMA2(sp( cvi), X[j], FMA2(sp(cwr), Ys[j], sp( cwi)*Xs[j])));
        X[j] = nX; Y[j] = nY;
    }
}

// cross-register gate: reg ja = row-A role, reg jb = row-B role
__device__ __forceinline__ void gateCross(float4 A, float4 B,
                                          v2& Xa, v2& Ya, v2& Xb, v2& Yb) {
    v2 nXa = FMA2(sp(A.x), Xa, FMA2(sp(-A.y), Ya, FMA2(sp(A.z), Xb, sp(-A.w)*Yb)));
    v2 nYa = FMA2(sp(A.x), Ya, FMA2(sp( A.y), Xa, FMA2(sp(A.z), Yb, sp( A.w)*Xb)));
    v2 nXb = FMA2(sp(B.x), Xa, FMA2(sp(-B.y), Ya, FMA2(sp(B.z), Xb, sp(-B.w)*Yb)));
    v2 nYb = FMA2(sp(B.x), Ya, FMA2(sp( B.y), Xa, FMA2(sp(B.z), Yb, sp( B.w)*Xb)));
    Xa = nXa; Ya = nYa; Xb = nXb; Yb = nYb;
}

// ---------------- main kernel: FOUR elements per wave, packed re/im ----------------
// element = 16-lane group; in-group lane u = lane&15.
// amp a6..a0 = u3 u2 u1 u0 k2 k1 k0. Register j = (k2<<1)|k0, component = k1.
//   X[j] = (re[amp(k1=0)], re[amp(k1=1)]),  Y[j] = imag pair.
// qubit q0->u3(m8) q1->u2(m4) q2->u1(m2) q3->u0(m1) q4->k2 q5->k1(comp) q6->k0
__global__ __launch_bounds__(256) void reupload_kernel(
    const float* __restrict__ x,       // (B,7)
    const float* __restrict__ wts,     // (4,7,3)
    const float* __restrict__ fc1_w,   // (32,7)
    const float* __restrict__ fc1_b,   // (32,)
    const float* __restrict__ fc2_w,   // (22,32)
    const float* __restrict__ fc2_b,   // (22,)
    float* __restrict__ out,           // (B,22)
    int B)
{
    __shared__ __align__(16) float rotU[NG * 8];        // 28 Rot matrices
    __shared__ float2 csb[EPB * NQ];                    // per-element RX (c,s)
    __shared__ __align__(16) float fU[NG * EPB * 8];    // fused matrices (14 KB)
    __shared__ __align__(16) float fUT[NL * EPB * 8];   // q5 transposed coefs (2 KB)
    __shared__ __align__(16) float hbuf[EPB][32];

    const int tid = threadIdx.x;
    // --- phase 0: c,s (112 thr) ∥ Rot matrices (28 thr on wave 2) ---
    if (tid < EPB * NQ) {
        const int e = tid / NQ, q = tid % NQ;
        const int bb = blockIdx.x * EPB + e;
        const float xv = (bb < B) ? x[bb*NQ + q] : 0.f;
        const float h = 0.5f * xv;
        csb[tid] = make_float2(__cosf(h), __sinf(h));
    } else if (tid >= 128 && tid < 128 + NG) {
        const int g = tid - 128;
        float phi = wts[g*3+0], th = wts[g*3+1], om = wts[g*3+2];
        float ct = __cosf(0.5f*th), st = __sinf(0.5f*th);
        float ap = 0.5f*(phi+om),  am = 0.5f*(phi-om);
        float cp = __cosf(ap), sp_ = __sinf(ap);
        float cm = __cosf(am), sm = __sinf(am);
        float* u = &rotU[g*8];
        u[0] =  cp*ct; u[1] = -sp_*ct;  // u00 = ep*ct        (ep = cp - i sp)
        u[2] = -cm*st; u[3] = -sm*st;   // u01 = -conj(em)*st (em = cm - i sm)
        u[4] =  cm*st; u[5] = -sm*st;   // u10 = em*st
        u[6] =  cp*ct; u[7] =  sp_*ct;  // u11 = conj(ep)*ct
    }
    __syncthreads();
    // --- phase 1: build fused matrices (448 = 2 per thread); q5 also transposed ---
    #pragma unroll
    for (int i = tid; i < NG * EPB; i += 256) {
        const int g = i >> 4, e = i & 15;
        const int q = g % NQ;
        const float2 cs = csb[e*NQ + q];
        float4 A, Bq;
        fuse(&rotU[g*8], cs.x, cs.y, A, Bq);
        float4* dst = reinterpret_cast<float4*>(&fU[(g*EPB + e)*8]);
        dst[0] = A; dst[1] = Bq;
        if (q == 5) {   // {(u00r,u10r),(u00i,u10i),(u01r,u11r),(u01i,u11i)}
            const int l = g / NQ;
            float* td = &fUT[(l*EPB + e)*8];
            td[0] = A.x; td[1] = Bq.x; td[2] = A.y; td[3] = Bq.y;
            td[4] = A.z; td[5] = Bq.z; td[6] = A.w; td[7] = Bq.w;
        }
    }
    __syncthreads();

    const int lane = threadIdx.x & 63;
    const int u    = threadIdx.x & 15;          // in-group lane
    const int grp  = threadIdx.x >> 4;          // element slot in block (0..15)
    const int b    = blockIdx.x * EPB + grp;
    if (b >= B) return;

    // merged CNOT(0,1)(1,2)(2,3) gather source: src_u = u ^ (u>>1) (R11-proven)
    const int srcLane = (lane & 48) | ((u ^ (u >> 1)) & 15);

    // |0..0>: amp 0 -> reg 0 comp .x at u==0
    v2 X[4], Y[4];
    #pragma unroll
    for (int j = 0; j < 4; ++j) { X[j] = sp(0.f); Y[j] = sp(0.f); }
    X[0].x = (u == 0) ? 1.f : 0.f;

    #pragma unroll
    for (int l = 0; l < NL; ++l) {
        float4 A, Bq;
        #define LOADU(q) { const float4* up = reinterpret_cast<const float4*>( \
            &fU[((l*NQ + (q))*EPB + grp)*8]); A = up[0]; Bq = up[1]; }
        LOADU(0); gateLane<8>(lane, A, Bq, X, Y);   // q0 -> u3
        LOADU(1); gateLane<4>(lane, A, Bq, X, Y);   // q1 -> u2
        LOADU(2); gateLane<2>(lane, A, Bq, X, Y);   // q2 -> u1
        LOADU(3); gateLane<1>(lane, A, Bq, X, Y);   // q3 -> u0
        LOADU(4);                                   // q4 -> k2: reg pairs (0,2),(1,3)
        gateCross(A, Bq, X[0], Y[0], X[2], Y[2]);
        gateCross(A, Bq, X[1], Y[1], X[3], Y[3]);
        {   // q5 -> k1: within-register, paired coefficients
            const v2* tp = reinterpret_cast<const v2*>(&fUT[(l*EPB + grp)*8]);
            const v2 c00r = tp[0], c00i = tp[1], c01r = tp[2], c01i = tp[3];
            #pragma unroll
            for (int j = 0; j < 4; ++j) {
                const v2 Xxx = X[j].xx, Xyy = X[j].yy;
                const v2 Yxx = Y[j].xx, Yyy = Y[j].yy;
                v2 nX = FMA2(c00r, Xxx, FMA2(-c00i, Yxx, FMA2(c01r, Xyy, (-c01i)*Yyy)));
                v2 nY = FMA2(c00r, Yxx, FMA2( c00i, Xxx, FMA2(c01r, Yyy, ( c01i)*Xyy)));
                X[j] = nX; Y[j] = nY;
            }
        }
        LOADU(6);                                   // q6 -> k0: reg pairs (0,1),(2,3)
        gateCross(A, Bq, X[0], Y[0], X[1], Y[1]);
        gateCross(A, Bq, X[2], Y[2], X[3], Y[3]);
        #undef LOADU

        // --- CNOT ring CNOT(q, q+1 mod 7), reference order q=0..6 ---
        // (0,1)+(1,2)+(2,3) merged: new[u] = old[u ^ (u>>1)] — one gather
        #pragma unroll
        for (int j = 0; j < 4; ++j) {
            X[j].x = __shfl(X[j].x, srcLane); X[j].y = __shfl(X[j].y, srcLane);
            Y[j].x = __shfl(Y[j].x, srcLane); Y[j].y = __shfl(Y[j].y, srcLane);
        }
        {   // (3,4): ctrl u0 (lane&1), tgt k2 -> cond swap regs (0<->2),(1<->3)
            const bool cc = (lane & 1) != 0;
            v2 t;
            t = X[0]; X[0] = sel(cc, X[2], X[0]); X[2] = sel(cc, t, X[2]);
            t = X[1]; X[1] = sel(cc, X[3], X[1]); X[3] = sel(cc, t, X[3]);
            t = Y[0]; Y[0] = sel(cc, Y[2], Y[0]); Y[2] = sel(cc, t, Y[2]);
            t = Y[1]; Y[1] = sel(cc, Y[3], Y[1]); Y[3] = sel(cc, t, Y[3]);
        }
        {   // (4,5): ctrl k2 (regs 2,3), tgt k1 -> component swap
            X[2] = X[2].yx; X[3] = X[3].yx; Y[2] = Y[2].yx; Y[3] = Y[3].yx;
        }
        {   // (5,6): ctrl k1 (.y comps), tgt k0 -> swap .y across reg-bit0 pairs
            float t;
            t = X[0].y; X[0].y = X[1].y; X[1].y = t;
            t = X[2].y; X[2].y = X[3].y; X[3].y = t;
            t = Y[0].y; Y[0].y = Y[1].y; Y[1].y = t;
            t = Y[2].y; Y[2].y = Y[3].y; Y[3].y = t;
        }
        {   // (6,0): ctrl k0 (regs 1,3), tgt u3 -> xor8 whole regs (DPP)
            X[1] = shufv<8>(X[1]); X[3] = shufv<8>(X[3]);
            Y[1] = shufv<8>(Y[1]); Y[3] = shufv<8>(Y[3]);
        }
    }

    // ---------- <Z_j> ----------
    v2 P[4];
    #pragma unroll
    for (int j = 0; j < 4; ++j) P[j] = FMA2(X[j], X[j], Y[j]*Y[j]);
    const v2 Sa = P[0] + P[1], Sb = P[2] + P[3];   // k2 = 0 / 1
    const v2 Se = P[0] + P[2], So = P[1] + P[3];   // k0 = 0 / 1
    const v2 T  = Sa + Sb;
    const float t = T.x + T.y;
    // z packed: zv[0]=(z0,z1), zv[1]=(z2,z3), zv[2]=(z4,z5), z6 scalar
    v2 zv[3];
    zv[0] = mkv2((lane & 8) ? -t : t, (lane & 4) ? -t : t);
    zv[1] = mkv2((lane & 2) ? -t : t, (lane & 1) ? -t : t);
    zv[2] = mkv2((Sa.x + Sa.y) - (Sb.x + Sb.y),   // sign by k2
                 T.x - T.y);                      // sign by k1 (component)
    float z6 = (Se.x + Se.y) - (So.x + So.y);     // sign by k0
    // 16-lane reduction (R12-proven chain), packed adds
    #pragma unroll
    for (int j = 0; j < 3; ++j) {
        v2 v = zv[j];
        v2 s1; s1.x = xorl<1>(v.x); s1.y = xorl<1>(v.y); v += s1;
        v2 s2; s2.x = xorl<2>(v.x); s2.y = xorl<2>(v.y); v += s2;
        v2 q4;  q4.x  = fdpp<0x124>(v.x); q4.y  = fdpp<0x124>(v.y);
        v2 q8;  q8.x  = fdpp<0x128>(v.x); q8.y  = fdpp<0x128>(v.y);
        v2 q12; q12.x = fdpp<0x12C>(v.x); q12.y = fdpp<0x12C>(v.y);
        zv[j] = (v + q8) + (q4 + q12);
    }
    {
        float v = z6;
        v += xorl<1>(v);
        v += xorl<2>(v);
        const float q4 = fdpp<0x124>(v), q8 = fdpp<0x128>(v), q12 = fdpp<0x12C>(v);
        z6 = (v + q8) + (q4 + q12);
    }

    // ---------- MLP 7 -> 32(relu) -> 22, per 16-lane group (2 rows/lane) ----------
    const float* wra = fc1_w + u*NQ;
    const float* wrb = fc1_w + (u+16)*NQ;
    v2 da = FMA2(zv[0], mkv2(wra[0], wra[1]),
            FMA2(zv[1], mkv2(wra[2], wra[3]),
                 zv[2] * mkv2(wra[4], wra[5])));
    v2 db = FMA2(zv[0], mkv2(wrb[0], wrb[1]),
            FMA2(zv[1], mkv2(wrb[2], wrb[3]),
                 zv[2] * mkv2(wrb[4], wrb[5])));
    const float acc1a = fc1_b[u]      + da.x + da.y + z6 * wra[6];
    const float acc1b = fc1_b[u + 16] + db.x + db.y + z6 * wrb[6];
    hbuf[grp][u]      = fmaxf(acc1a, 0.f);
    hbuf[grp][u + 16] = fmaxf(acc1b, 0.f);
    __builtin_amdgcn_wave_barrier();
    asm volatile("s_waitcnt lgkmcnt(0)" ::: "memory");
    __builtin_amdgcn_sched_barrier(0);

    v2 hv[16];
    #pragma unroll
    for (int i = 0; i < 8; ++i) {   // broadcast reads within each group
        float4 v4 = *reinterpret_cast<const float4*>(&hbuf[grp][i*4]);
        hv[2*i]   = mkv2(v4.x, v4.y);
        hv[2*i+1] = mkv2(v4.z, v4.w);
    }
    const int kb = (u < NCLS - 16) ? (u + 16) : 0;   // clamp row for u>=6
    const float4* w4a = reinterpret_cast<const float4*>(fc2_w + u*32);
    const float4* w4b = reinterpret_cast<const float4*>(fc2_w + kb*32);
    v2 a2 = sp(0.f), b2 = sp(0.f);
    #pragma unroll
    for (int i = 0; i < 8; ++i) {
        float4 wa = w4a[i], wb = w4b[i];
        a2 = FMA2(hv[2*i],   mkv2(wa.x, wa.y), a2);
        a2 = FMA2(hv[2*i+1], mkv2(wa.z, wa.w), a2);
        b2 = FMA2(hv[2*i],   mkv2(wb.x, wb.y), b2);
        b2 = FMA2(hv[2*i+1], mkv2(wb.z, wb.w), b2);
    }
    const float acc2a = fc2_b[u]  + a2.x + a2.y;
    const float acc2b = fc2_b[kb] + b2.x + b2.y;
    out[b*NCLS + u] = acc2a;
    if (u < NCLS - 16) out[b*NCLS + 16 + u] = acc2b;
}

extern "C" void kernel_launch(void* const* d_in, const int* in_sizes, int n_in,
                              void* d_out, int out_size, void* d_ws, size_t ws_size,
                              hipStream_t stream) {
    const float* x     = (const float*)d_in[0];
    const float* wts   = (const float*)d_in[1];
    const float* fc1_w = (const float*)d_in[2];
    const float* fc1_b = (const float*)d_in[3];
    const float* fc2_w = (const float*)d_in[4];
    const float* fc2_b = (const float*)d_in[5];
    float* out = (float*)d_out;

    const int B = in_sizes[0] / NQ;            // 16384
    const int grid = (B + EPB - 1) / EPB;      // 1024 blocks
    reupload_kernel<<<grid, 256, 0, stream>>>(x, wts, fc1_w, fc1_b, fc2_w, fc2_b, out, B);
}